// Round 1
// 184.724 us; speedup vs baseline: 1.0013x; 1.0013x over previous
//
#include <hip/hip_runtime.h>
#include <stdint.h>

// NextPanelHead: logits[b,i,j] = P[b,i] . W . P[b,j] + bias
// B=8, N=2048, D=384. PW = P@W (GEMM1), logits = PW @ P^T (GEMM2), fp16 MFMA
// (threshold 2.38 licenses 16-bit inputs), fp32 accumulate.
// Round 6: GEMM2 rewritten as 256x256-tile 8-wave 8-subphase pipeline:
//  - 2 full K-tile LDS buffers (128 KB), raw s_barrier (NO vmcnt drain),
//    exactly two s_waitcnt vmcnt(0) per 2-K-tile iteration, each >=3
//    sub-phases after the youngest guarded global_load_lds (T3+T4).
//  - staging phases disjoint from reading phases per buffer -> race-free
//    without __syncthreads' full drain.
//  - s_setprio(1) around each 8-MFMA cluster (T5; phase role-split exists).
//  - bias folded into acc init (MFMA C-in), epilogue adds removed.
//  - B-frags held in regs across mh-phase pairs (LDS BW ~94 B/cyc < ceiling).
// Unchanged: prep, GEMM1, XOR LDS swizzle scheme, global_load_lds w=16,
// XCD decode (GEMM2 pins batch to XCD; PW+Ph 3.1 MB L2-resident per XCD).

#define BATCH 8
#define NSEQ  2048
#define DDIM  384
#define BM 128
#define BN 128
#define BK 64

#define G2_BM 256
#define G2_BN 256

typedef __attribute__((ext_vector_type(8)))  _Float16 half8;
typedef __attribute__((ext_vector_type(16))) float    f32x16;

#define NP (BATCH * NSEQ * DDIM)   // 6,291,456
#define CAST_BLOCKS 1024

// ---- prep: cast P fp32->fp16 (blocks 0..1023) + transpose-cast W (rest) ----
__global__ void prep_kernel(const float* __restrict__ P,
                            const float* __restrict__ W,
                            _Float16* __restrict__ Ph,
                            _Float16* __restrict__ Wt) {
    if (blockIdx.x < CAST_BLOCKS) {
        int i = (blockIdx.x * 256 + threadIdx.x) * 8;
        const int stride = CAST_BLOCKS * 256 * 8;
        for (; i < NP; i += stride) {
            float4 f0 = *(const float4*)(P + i);
            float4 f1 = *(const float4*)(P + i + 4);
            half8 h;
            h[0] = (_Float16)f0.x; h[1] = (_Float16)f0.y;
            h[2] = (_Float16)f0.z; h[3] = (_Float16)f0.w;
            h[4] = (_Float16)f1.x; h[5] = (_Float16)f1.y;
            h[6] = (_Float16)f1.z; h[7] = (_Float16)f1.w;
            *(half8*)(Ph + i) = h;
        }
    } else {
        int o = (blockIdx.x - CAST_BLOCKS) * 256 + threadIdx.x;  // o = e*384+d
        if (o < DDIM * DDIM) {
            int e = o / DDIM;
            int d = o - e * DDIM;
            Wt[o] = (_Float16)W[d * DDIM + e];
        }
    }
}

// ---- GEMM1: PW[16384x384] = Ph[16384x384] . Wt^T, 128x64 tile, fp16 out ----
// 1D grid of 768; XCD swizzle: xcd = n&7 owns y in {xcd, xcd+8, ...} (16 rows)
__global__ __launch_bounds__(256, 4) void gemm1_kernel(
    const _Float16* __restrict__ A,     // 16384 x 384
    const _Float16* __restrict__ Bmat,  // 384 x 384 (Wt = W^T)
    _Float16* __restrict__ C) {         // 16384 x 384
    __shared__ _Float16 As[BM * BK];    // 16 KB
    __shared__ _Float16 Bs[64 * BK];    // 8 KB

    const int n   = blockIdx.x;
    const int xcd = n & 7;
    const int i2  = n >> 3;        // 0..95
    const int bx  = i2 % 6;        // col tile 0..5
    const int by  = xcd + 8 * (i2 / 6);  // row tile 0..127

    const _Float16* Ab = A + (size_t)by * BM * DDIM;
    const _Float16* Bb = Bmat + (size_t)bx * 64 * DDIM;

    const int tid  = threadIdx.x;
    const int wave = tid >> 6;    // 0..3 = row band
    const int lane = tid & 63;
    const int lm   = lane & 31;
    const int hi   = lane >> 5;

    const int srow = tid >> 3;                      // 0..31
    const int scg  = ((tid & 7) ^ (srow & 7)) * 8;  // swizzled global k off

    const int h0    = (hi ^ (lm & 7)) * 16;
    const int baseA = (wave * 32 + lm) * (BK * 2) + h0;
    const int baseB0 = lm * (BK * 2) + h0;
    const int baseB1 = (32 + lm) * (BK * 2) + h0;
    const char* AsB = (const char*)As;
    const char* BsB = (const char*)Bs;

    f32x16 acc0, acc1;
#pragma unroll
    for (int r = 0; r < 16; ++r) { acc0[r] = 0.f; acc1[r] = 0.f; }

    for (int k0 = 0; k0 < DDIM; k0 += BK) {
#pragma unroll
        for (int p = 0; p < 4; ++p) {
            __builtin_amdgcn_global_load_lds(
                (const __attribute__((address_space(1))) void*)
                    (Ab + (size_t)(p * 32 + srow) * DDIM + k0 + scg),
                (__attribute__((address_space(3))) void*)
                    (As + (p * 256 + tid) * 8),
                16, 0, 0);
        }
#pragma unroll
        for (int p = 0; p < 2; ++p) {
            __builtin_amdgcn_global_load_lds(
                (const __attribute__((address_space(1))) void*)
                    (Bb + (size_t)(p * 32 + srow) * DDIM + k0 + scg),
                (__attribute__((address_space(3))) void*)
                    (Bs + (p * 256 + tid) * 8),
                16, 0, 0);
        }
        __syncthreads();
#pragma unroll
        for (int s = 0; s < 4; ++s) {
            const int sx = s * 32;
            half8 a  = *(const half8*)(AsB + (baseA ^ sx));
            half8 b0 = *(const half8*)(BsB + (baseB0 ^ sx));
            half8 b1 = *(const half8*)(BsB + (baseB1 ^ sx));
            acc0 = __builtin_amdgcn_mfma_f32_32x32x16_f16(a, b0, acc0, 0, 0, 0);
            acc1 = __builtin_amdgcn_mfma_f32_32x32x16_f16(a, b1, acc1, 0, 0, 0);
        }
        __syncthreads();
    }

    const size_t row_base = (size_t)by * BM + wave * 32;
    const size_t col_base = (size_t)bx * 64;
#pragma unroll
    for (int reg = 0; reg < 16; ++reg) {
        const int rin = (reg & 3) + 8 * (reg >> 2) + 4 * hi;
        _Float16* row = C + (row_base + rin) * DDIM + col_base;
        row[lm]      = (_Float16)acc0[reg];
        row[32 + lm] = (_Float16)acc1[reg];
    }
}

// ---- GEMM2: out[b] = PW[b] . Ph[b]^T + bias, 256x256 tile, 8 waves -------
// 1D grid of 512; xcd = n&7 = batch z -> each XCD's L2 holds its batch's
// PW (1.57 MB) + Ph (1.57 MB); all tile reuse served from L2.
// Pipeline: 2 K-tile buffers; iter consumes tiles {2i (buf0), 2i+1 (buf1)}
// over 8 sub-phases (quadrant = (kh, mh), 8 MFMA each). Stages: buf1 gets
// tile 2i+1 at sub-phases 0-1; buf0 gets tile 2i+2 at sub-phases 4-5.
// Reads/writes per buffer are phase-disjoint -> raw s_barrier is safe;
// vmcnt(0) only at sub-phase 0 and 4 (>=3 phases after youngest load).

#define G2_BAR() do { asm volatile("" ::: "memory");                       \
    __builtin_amdgcn_s_barrier(); asm volatile("" ::: "memory"); } while (0)
#define G2_VMW() asm volatile("s_waitcnt vmcnt(0)" ::: "memory")

#define G2_STAGE_A(buf, k0)                                                \
    _Pragma("unroll")                                                      \
    for (int hl = 0; hl < 4; ++hl) {                                       \
        __builtin_amdgcn_global_load_lds(                                  \
            (const __attribute__((address_space(1))) void*)                \
                (Ab + (size_t)(hl * 64 + srow) * DDIM + (k0) + scg),       \
            (__attribute__((address_space(3))) void*)                      \
                (&As[buf][0] + (hl * 512 + tid) * 8),                      \
            16, 0, 0);                                                     \
    }

#define G2_STAGE_B(buf, k0)                                                \
    _Pragma("unroll")                                                      \
    for (int hl = 0; hl < 4; ++hl) {                                       \
        __builtin_amdgcn_global_load_lds(                                  \
            (const __attribute__((address_space(1))) void*)                \
                (Bb + (size_t)(hl * 64 + srow) * DDIM + (k0) + scg),       \
            (__attribute__((address_space(3))) void*)                      \
                (&Bs[buf][0] + (hl * 512 + tid) * 8),                      \
            16, 0, 0);                                                     \
    }

// one sub-phase: quadrant (kh, mh); loads B-frags when mh==0, reuses at mh==1
#define G2_PHASE(AP, BP, kh, mh, LOADB)                                    \
    do {                                                                   \
        if (LOADB) {                                                       \
            _Pragma("unroll")                                              \
            for (int nh = 0; nh < 2; ++nh)                                 \
                _Pragma("unroll")                                          \
                for (int k2 = 0; k2 < 2; ++k2)                             \
                    bfrag[nh][k2] = *(const half8*)((BP)                   \
                        + ((baseB + nh * 4096) ^ ((kh) * 64) ^ (k2 * 32)));\
        }                                                                  \
        half8 afr[2][2];                                                   \
        _Pragma("unroll")                                                  \
        for (int rs = 0; rs < 2; ++rs)                                     \
            _Pragma("unroll")                                              \
            for (int k2 = 0; k2 < 2; ++k2)                                 \
                afr[rs][k2] = *(const half8*)((AP)                         \
                    + ((baseA + (mh) * 8192 + rs * 4096)                   \
                       ^ ((kh) * 64) ^ (k2 * 32)));                        \
        __builtin_amdgcn_s_setprio(1);                                     \
        _Pragma("unroll")                                                  \
        for (int k2 = 0; k2 < 2; ++k2)                                     \
            _Pragma("unroll")                                              \
            for (int rs = 0; rs < 2; ++rs)                                 \
                _Pragma("unroll")                                          \
                for (int nh = 0; nh < 2; ++nh)                             \
                    acc[(mh) * 2 + rs][nh] =                               \
                        __builtin_amdgcn_mfma_f32_32x32x16_f16(            \
                            afr[rs][k2], bfrag[nh][k2],                    \
                            acc[(mh) * 2 + rs][nh], 0, 0, 0);              \
        __builtin_amdgcn_s_setprio(0);                                     \
    } while (0)

__global__ __launch_bounds__(512, 2) void gemm2_kernel(
    const _Float16* __restrict__ A,     // PW: per-batch 2048 x 384
    const _Float16* __restrict__ Bmat,  // Ph: per-batch 2048 x 384
    float* __restrict__ C,              // per-batch 2048 x 2048
    const float* __restrict__ bias_ptr) {
    __shared__ _Float16 As[2][G2_BM * BK];  // 2 x 32 KB
    __shared__ _Float16 Bs[2][G2_BN * BK];  // 2 x 32 KB  -> 128 KB total

    const int n  = blockIdx.x;
    const int z  = n & 7;          // batch == XCD
    const int i2 = n >> 3;         // 0..63
    const int bx = i2 & 7;
    const int by = i2 >> 3;

    const size_t bstride = (size_t)NSEQ * DDIM;
    const _Float16* Ab = A + (size_t)z * bstride + (size_t)by * G2_BM * DDIM;
    const _Float16* Bb = Bmat + (size_t)z * bstride + (size_t)bx * G2_BN * DDIM;

    const int tid  = threadIdx.x;
    const int wave = tid >> 6;    // 0..7
    const int lane = tid & 63;
    const int wr   = wave >> 2;   // 0..1: rows wr*128..+128
    const int wc   = wave & 3;    // 0..3: cols wc*64..+64
    const int lm   = lane & 31;
    const int hi   = lane >> 5;

    const int srow = tid >> 3;                      // 0..63
    const int scg  = ((tid & 7) ^ (srow & 7)) * 8;  // swizzled global k off

    const int swz   = (hi ^ (lm & 7)) * 16;
    const int baseA = (wr * 128 + lm) * (BK * 2) + swz;  // byte off in As[b]
    const int baseB = (wc * 64 + lm) * (BK * 2) + swz;   // byte off in Bs[b]
    const char* A0 = (const char*)&As[0][0];
    const char* A1 = (const char*)&As[1][0];
    const char* B0 = (const char*)&Bs[0][0];
    const char* B1 = (const char*)&Bs[1][0];

    // bias folded into accumulator init (MFMA C-in adds it exactly once)
    const float bias = bias_ptr[0];
    f32x16 acc[4][2];
#pragma unroll
    for (int ri = 0; ri < 4; ++ri)
#pragma unroll
        for (int ci = 0; ci < 2; ++ci)
#pragma unroll
            for (int r = 0; r < 16; ++r) acc[ri][ci][r] = bias;

    half8 bfrag[2][2];

    // prologue: tile 0 -> buf0
    G2_STAGE_A(0, 0);
    G2_STAGE_B(0, 0);

#pragma unroll
    for (int it = 0; it < 3; ++it) {
        const int kr1 = it * 128 + 64;   // tile 2it+1 -> buf1
        const int kn  = it * 128 + 128;  // tile 2it+2 -> buf0 (if exists)

        // ---- sub-phases 0-3: read buf0 (tile 2it); stage buf1
        G2_VMW();              // buf0 loads (issued >=3 phases ago) landed
        G2_BAR();
        G2_STAGE_A(1, kr1);
        G2_PHASE(A0, B0, 0, 0, 1);
        G2_BAR();
        G2_STAGE_B(1, kr1);
        G2_PHASE(A0, B0, 0, 1, 0);
        G2_BAR();
        G2_PHASE(A0, B0, 1, 0, 1);
        G2_BAR();
        G2_PHASE(A0, B0, 1, 1, 0);

        // ---- sub-phases 4-7: read buf1 (tile 2it+1); stage buf0
        G2_VMW();              // buf1 loads (issued sub-phases 0-1) landed
        G2_BAR();
        if (it < 2) G2_STAGE_A(0, kn);
        G2_PHASE(A1, B1, 0, 0, 1);
        G2_BAR();
        if (it < 2) G2_STAGE_B(0, kn);
        G2_PHASE(A1, B1, 0, 1, 0);
        G2_BAR();
        G2_PHASE(A1, B1, 1, 0, 1);
        G2_BAR();
        G2_PHASE(A1, B1, 1, 1, 0);
    }

    // C/D layout: col = lane&31, row = (reg&3) + 8*(reg>>2) + 4*hi.
    float* Cb = C + (size_t)z * NSEQ * NSEQ;
    const size_t row_base = (size_t)by * G2_BM + wr * 128;
    const size_t col_base = (size_t)bx * G2_BN + wc * 64;
#pragma unroll
    for (int ri = 0; ri < 4; ++ri)
#pragma unroll
        for (int ci = 0; ci < 2; ++ci)
#pragma unroll
            for (int reg = 0; reg < 16; ++reg) {
                const int rin = (reg & 3) + 8 * (reg >> 2) + 4 * hi;
                Cb[(row_base + ri * 32 + rin) * NSEQ
                   + col_base + ci * 32 + lm] = acc[ri][ci][reg];
            }
}

extern "C" void kernel_launch(void* const* d_in, const int* in_sizes, int n_in,
                              void* d_out, int out_size, void* d_ws,
                              size_t ws_size, hipStream_t stream) {
    const float* P  = (const float*)d_in[0];  // [8,2048,384]
    const float* W  = (const float*)d_in[1];  // [384,384]
    const float* bp = (const float*)d_in[2];  // [1]
    float* out = (float*)d_out;               // [8,2048,2048]

    // workspace (fp16): Ph 12.6MB | Wt 0.3MB | PW 12.6MB
    _Float16* Ph = (_Float16*)d_ws;
    _Float16* Wt = Ph + (size_t)NP;
    _Float16* PW = Wt + (size_t)DDIM * DDIM;

    const int wblocks = (DDIM * DDIM + 255) / 256;  // 576
    prep_kernel<<<CAST_BLOCKS + wblocks, 256, 0, stream>>>(P, W, Ph, Wt);

    // GEMM1: 768 blocks (1D, XCD-swizzled decode inside)
    gemm1_kernel<<<768, 256, 0, stream>>>(Ph, Wt, PW);

    // GEMM2: 512 blocks of 512 threads (xcd = batch decode inside)
    gemm2_kernel<<<512, 512, 0, stream>>>(PW, Ph, out, bp);
}